// Round 2
// baseline (43.362 us; speedup 1.0000x reference)
//
#include <hip/hip_runtime.h>

// NoiseLearnModule: out = x + where(0<=bin<16, eps * sigmoid(params[f,bin]) * 0.1, 0)
// bin = searchsorted(bins[f], x, side='right') - 1
// x,eps [65536,256] f32; bins [256,17] f32; params [256*16] f32.
//
// Structure: 2 features/thread, bin edges held in REGISTERS (loop-invariant),
// sigmoid table in 16 KB transposed LDS (4-way-conflict gather), float2 I/O.

#define NFEAT 256
#define NBINS 16
#define NEDGE 17
#define NOISE_SCALE 0.1f

__global__ __launch_bounds__(256, 8) void noise_learn_kernel(
    const float* __restrict__ x,
    const float* __restrict__ bins,
    const float* __restrict__ eps,
    const float* __restrict__ params,
    float* __restrict__ out,
    int total2)
{
    // One reused LDS buffer: first bins [f][e] (natural), then sigmoid [k][f] (transposed).
    __shared__ float s_mem[NEDGE * NFEAT];   // 17408 B

    const int t = threadIdx.x;

    // Coalesced stage of bins into LDS (natural layout)
    #pragma unroll
    for (int i = t; i < NEDGE * NFEAT; i += 256)   // 17 exact iters
        s_mem[i] = bins[i];
    __syncthreads();

    const int gid = blockIdx.x * 256 + t;
    const int f0 = (gid & 127) * 2;   // stride is a multiple of 128 -> loop-invariant
    const int f1 = f0 + 1;

    // Hoist this thread's two features' edges into registers (one-time).
    float e0[NEDGE], e1[NEDGE];
    #pragma unroll
    for (int e = 0; e < NEDGE; ++e) {
        e0[e] = s_mem[f0 * NEDGE + e];
        e1[e] = s_mem[f1 * NEDGE + e];
    }
    __syncthreads();

    // Overwrite LDS with transposed sigmoid table: s[k][f]
    #pragma unroll
    for (int k = 0; k < NBINS; ++k) {
        float p = params[t * NBINS + k];
        s_mem[k * NFEAT + t] = 1.0f / (1.0f + expf(-p));
    }
    __syncthreads();

    const int stride = gridDim.x * 256;
    for (int g = gid; g < total2; g += stride) {
        const float2 xv = reinterpret_cast<const float2*>(x)[g];
        const float2 ev = reinterpret_cast<const float2*>(eps)[g];

        int c0 = 0, c1 = 0;   // count of edges <= x  (searchsorted 'right')
        #pragma unroll
        for (int e = 0; e < NEDGE; ++e) {
            c0 += (e0[e] <= xv.x) ? 1 : 0;
            c1 += (e1[e] <= xv.y) ? 1 : 0;
        }

        float2 ov;
        {
            const int idx = c0 - 1;
            const int jc = idx < 0 ? 0 : (idx > NBINS - 1 ? NBINS - 1 : idx);
            const float sc = s_mem[jc * NFEAT + f0];
            ov.x = xv.x + (((unsigned)idx < (unsigned)NBINS) ? ev.x * sc * NOISE_SCALE : 0.0f);
        }
        {
            const int idx = c1 - 1;
            const int jc = idx < 0 ? 0 : (idx > NBINS - 1 ? NBINS - 1 : idx);
            const float sc = s_mem[jc * NFEAT + f1];
            ov.y = xv.y + (((unsigned)idx < (unsigned)NBINS) ? ev.y * sc * NOISE_SCALE : 0.0f);
        }

        reinterpret_cast<float2*>(out)[g] = ov;
    }
}

extern "C" void kernel_launch(void* const* d_in, const int* in_sizes, int n_in,
                              void* d_out, int out_size, void* d_ws, size_t ws_size,
                              hipStream_t stream) {
    const float* x      = (const float*)d_in[0];
    const float* bins   = (const float*)d_in[1];
    const float* eps    = (const float*)d_in[2];
    const float* params = (const float*)d_in[3];
    float* out = (float*)d_out;

    const int total2 = out_size / 2;   // 8,388,608 float2 groups
    dim3 block(256);
    dim3 grid(2048);                   // 8 blocks/CU -> fully resident at 100% occupancy
    noise_learn_kernel<<<grid, block, 0, stream>>>(x, bins, eps, params, out, total2);
}